// Round 6
// baseline (486.273 us; speedup 1.0000x reference)
//
#include <hip/hip_runtime.h>

// GNN_MLP R6: planar-feature conv2 (8 float2 planes of 4MB, each L2-resident
// during its sweep) + two-level bucket partition (256 super -> x8 fine).
// R3/R4/R5 all plateaued at ~222us on conv2: FETCH=160MB=E*64B proved the
// interleaved h1 gather misses all caches (32MB >> 4MB/XCD L2). Planar
// planes shrink the gather working set to 4MB.
// Algebra: conv = segsum((h@W+b)[src],dst) = segsum(h[src])@W + indeg*b.

#define TPB 256
#define SBK_BITS 11           // super-bucket = 2048 nodes
#define NSB_MAX 256
#define CAP1 11264            // edges per super-bucket (mean 10240, +10 sigma)
#define PE1 8192              // edges per pass-1 block
#define BKT_BITS 8
#define BKT 256               // nodes per fine bucket
#define CAPF 1536             // edges per fine bucket (mean 1280, +7 sigma)
#define ASTRIDE 257           // conv2 LDS acc feature-row stride

__device__ __forceinline__ float reluf(float v) { return v > 0.f ? v : 0.f; }

// pass 1: partition edges into 2048-node super-buckets, word = src<<11 | dst&2047
__global__ void kPart1(const int* __restrict__ src, const int* __restrict__ dst,
                       int* __restrict__ cur1, int* __restrict__ part1, int E) {
    __shared__ int h[NSB_MAX];
    h[threadIdx.x] = 0;
    __syncthreads();
    int base = blockIdx.x * PE1;
    int end = base + PE1 < E ? base + PE1 : E;
    for (int e = base + threadIdx.x; e < end; e += TPB)
        atomicAdd(&h[dst[e] >> SBK_BITS], 1);
    __syncthreads();
    {
        int c = h[threadIdx.x];
        if (c) h[threadIdx.x] = threadIdx.x * CAP1 + atomicAdd(&cur1[threadIdx.x], c);
    }
    __syncthreads();
    for (int e = base + threadIdx.x; e < end; e += TPB) {
        int d = dst[e];
        int sb = d >> SBK_BITS;
        int pos = atomicAdd(&h[sb], 1);
        if (pos < (sb + 1) * CAP1)
            part1[pos] = (src[e] << SBK_BITS) | (d & 2047);
    }
}

// pass 2: split each super-bucket into 8 fine buckets; 2 blocks per super.
// out word = src<<8 | dst&255.
__global__ void kPart2(const int* __restrict__ cur1, const int* __restrict__ part1,
                       int* __restrict__ curF, int* __restrict__ partF) {
    int sb = blockIdx.x >> 1, half = blockIdx.x & 1;
    int cnt = cur1[sb]; if (cnt > CAP1) cnt = CAP1;
    int mid = (cnt + 1) >> 1;
    int rs = sb * CAP1 + (half ? mid : 0);
    int re = sb * CAP1 + (half ? cnt : mid);
    __shared__ int hw[4][8];
    __shared__ int cbase[8];
    if (threadIdx.x < 32) hw[threadIdx.x >> 3][threadIdx.x & 7] = 0;
    __syncthreads();
    int wv = threadIdx.x >> 6;
    for (int i = rs + threadIdx.x; i < re; i += TPB)
        atomicAdd(&hw[wv][(part1[i] >> 8) & 7], 1);
    __syncthreads();
    if (threadIdx.x < 8) {
        int c = hw[0][threadIdx.x] + hw[1][threadIdx.x] + hw[2][threadIdx.x] + hw[3][threadIdx.x];
        int fb = sb * 8 + threadIdx.x;
        cbase[threadIdx.x] = fb * CAPF + (c ? atomicAdd(&curF[fb], c) : 0);
    }
    __syncthreads();
    for (int i = rs + threadIdx.x; i < re; i += TPB) {
        int w = part1[i];
        int f = (w >> 8) & 7;
        int pos = atomicAdd(&cbase[f], 1);
        if (pos < (sb * 8 + f + 1) * CAPF)
            partF[pos] = ((w >> 11) << 8) | (w & 255);
    }
}

// conv1: one block per fine bucket; LDS-accumulate raw x + degree, W1+relu,
// write h1 as 8 planar float2 planes (plane stride N).
__global__ void __launch_bounds__(TPB, 8)
kConv1(const float* __restrict__ x, const int* __restrict__ partF,
       const int* __restrict__ curF,
       const float* __restrict__ W1, const float* __restrict__ b1,
       float2* __restrict__ h1p, int* __restrict__ deg, int N) {
    __shared__ float ax[BKT * 3];
    __shared__ int cnt[BKT];
    int b = blockIdx.x, node0 = b << BKT_BITS;
    ax[3 * threadIdx.x] = 0.f; ax[3 * threadIdx.x + 1] = 0.f;
    ax[BKT * 2 + threadIdx.x] = 0.f;   // fill rest (unused slots) for safety
    cnt[threadIdx.x] = 0;
    __syncthreads();
    int rs = b * CAPF;
    int ec = curF[b]; if (ec > CAPF) ec = CAPF;
    int re = rs + ec;
    for (int e = rs + threadIdx.x; e < re; e += TPB) {
        int w = partF[e];
        int s = w >> BKT_BITS, l = w & (BKT - 1);
        float2 xv = ((const float2*)x)[s];
        atomicAdd(&ax[3 * l], xv.x);
        atomicAdd(&ax[3 * l + 1], xv.y);
        atomicAdd(&cnt[l], 1);
    }
    __syncthreads();
    int l = threadIdx.x;
    int i = node0 + l;
    if (i < N) {
        float2 s2 = ((const float2*)x)[i];
        float a0 = ax[3 * l] + s2.x, a1 = ax[3 * l + 1] + s2.y;
        int indeg = cnt[l] + 1;      // + self loop
        float degf = (float)indeg;
        float h[16];
#pragma unroll
        for (int j = 0; j < 16; j++)
            h[j] = reluf(fmaf(a0, W1[j], fmaf(a1, W1[16 + j], degf * b1[j])));
#pragma unroll
        for (int fp = 0; fp < 8; fp++)
            h1p[(size_t)fp * N + i] = make_float2(h[2 * fp], h[2 * fp + 1]);
        deg[i] = indeg;
    }
}

// conv2: stage bucket edges in LDS, sweep 8 planar float2 planes (4MB each,
// L2-resident), accumulate in LDS, then W2+relu -> h2 [N,32].
__global__ void __launch_bounds__(TPB, 6)
kConv2(const float2* __restrict__ h1p, const int* __restrict__ partF,
       const int* __restrict__ curF, const int* __restrict__ deg,
       const float* __restrict__ W2, const float* __restrict__ b2,
       float* __restrict__ h2, int N) {
    __shared__ int eidx[CAPF];            // 6 KB
    __shared__ float acc[16 * ASTRIDE];   // 16.4 KB
    int b = blockIdx.x, node0 = b << BKT_BITS;
    for (int i = threadIdx.x; i < 16 * ASTRIDE; i += TPB) acc[i] = 0.f;
    int rs = b * CAPF;
    int ec = curF[b]; if (ec > CAPF) ec = CAPF;
    for (int i = threadIdx.x; i < ec; i += TPB) eidx[i] = partF[rs + i];
    __syncthreads();
    for (int fp = 0; fp < 8; fp++) {
        const float2* plane = h1p + (size_t)fp * N;
        float* r0 = &acc[(2 * fp) * ASTRIDE];
        float* r1 = &acc[(2 * fp + 1) * ASTRIDE];
        for (int k = threadIdx.x; k < ec; k += TPB) {
            int w = eidx[k];
            int s = w >> BKT_BITS, l = w & (BKT - 1);
            float2 v = plane[s];
            atomicAdd(r0 + l, v.x);
            atomicAdd(r1 + l, v.y);
        }
        __syncthreads();   // keep all waves on the same plane (L2 locality)
    }
    int l = threadIdx.x;
    int i = node0 + l;
    if (i < N) {
        float a[16];
#pragma unroll
        for (int fp = 0; fp < 8; fp++) {
            float2 sv = h1p[(size_t)fp * N + i];
            a[2 * fp]     = acc[(2 * fp) * ASTRIDE + l] + sv.x;
            a[2 * fp + 1] = acc[(2 * fp + 1) * ASTRIDE + l] + sv.y;
        }
        float degf = (float)deg[i];
        float4* ov = (float4*)(h2 + 32 * (size_t)i);
#pragma unroll
        for (int q = 0; q < 8; q++) {
            float4 r;
            float* rp = &r.x;
#pragma unroll
            for (int jj = 0; jj < 4; jj++) {
                int j = 4 * q + jj;
                float vv = degf * b2[j];
#pragma unroll
                for (int k = 0; k < 16; k++) vv = fmaf(a[k], W2[k * 32 + j], vv);
                rp[jj] = reluf(vv);
            }
            ov[q] = r;
        }
    }
}

__device__ __forceinline__ int lower_bound(const int* __restrict__ a, int n, int v) {
    int lo = 0, hi = n;
    while (lo < hi) {
        int m = (lo + hi) >> 1;
        if (a[m] < v) lo = m + 1; else hi = m;
    }
    return lo;
}

// mean pool per graph (batch sorted -> binary search range) + fused MLP head
__global__ void kPoolMLP(const float* __restrict__ h2, const int* __restrict__ batch,
                         const float* __restrict__ Wf1, const float* __restrict__ bf1,
                         const float* __restrict__ Wf2, const float* __restrict__ bf2,
                         float* __restrict__ out, int N) {
    int g = blockIdx.x;
    int lo = lower_bound(batch, N, g);
    int hi = lower_bound(batch, N, g + 1);
    int cnt = hi - lo;
    int f = threadIdx.x & 31;
    int r = threadIdx.x >> 5;
    float acc = 0.f;
    for (int n = lo + r; n < hi; n += 8)
        acc += h2[32 * (size_t)n + f];
    __shared__ float s[8][33];
    __shared__ float p[32];
    __shared__ float v16[16];
    s[r][f] = acc;
    __syncthreads();
    if (r == 0) {
        float t = 0.f;
#pragma unroll
        for (int q = 0; q < 8; q++) t += s[q][f];
        p[f] = t / (float)(cnt > 1 ? cnt : 1);
    }
    __syncthreads();
    if (threadIdx.x < 16) {
        int j = threadIdx.x;
        float v = bf1[j];
#pragma unroll
        for (int i = 0; i < 32; i++) v = fmaf(p[i], Wf1[i * 16 + j], v);
        v16[j] = reluf(v);
    }
    __syncthreads();
    if (threadIdx.x == 0) {
        float a = bf2[0];
#pragma unroll
        for (int j = 0; j < 16; j++) a = fmaf(v16[j], Wf2[j], a);
        out[g] = a;
    }
}

static inline size_t align256(size_t v) { return (v + 255) & ~(size_t)255; }

extern "C" void kernel_launch(void* const* d_in, const int* in_sizes, int n_in,
                              void* d_out, int out_size, void* d_ws, size_t ws_size,
                              hipStream_t stream) {
    const float* x    = (const float*)d_in[0];
    const int*   ei   = (const int*)d_in[1];
    const int*   batch= (const int*)d_in[2];
    const float* W1   = (const float*)d_in[3];
    const float* b1   = (const float*)d_in[4];
    const float* W2   = (const float*)d_in[5];
    const float* b2   = (const float*)d_in[6];
    const float* Wf1  = (const float*)d_in[7];
    const float* bf1  = (const float*)d_in[8];
    const float* Wf2  = (const float*)d_in[9];
    const float* bf2  = (const float*)d_in[10];
    float* out = (float*)d_out;

    const int N = in_sizes[0] / 2;
    const int E = in_sizes[1] / 2;
    const int G = out_size;
    const int* src = ei;        // edge_index[0]
    const int* dst = ei + E;    // edge_index[1]

    const int NSB = (N + 2047) >> SBK_BITS;          // super-buckets (<=256)
    const int NFB = (N + BKT - 1) >> BKT_BITS;       // fine buckets

    // workspace layout; part1 overlays h2 (disjoint lifetimes)
    char* w = (char*)d_ws;
    int*   cur1 = (int*)w;    w += align256((size_t)NSB_MAX * sizeof(int));
    int*   curF = (int*)w;    w += align256((size_t)NSB_MAX * 8 * sizeof(int));
    int*   deg  = (int*)w;    w += align256((size_t)N * sizeof(int));
    float2* h1p = (float2*)w; w += align256((size_t)N * 16 * sizeof(float));
    float* h2   = (float*)w;  w += align256((size_t)N * 32 * sizeof(float));
    int*   part1 = (int*)h2;  // overlay: dead before kConv2 writes h2
    int*   partF = (int*)w;   w += align256((size_t)NSB_MAX * 8 * CAPF * sizeof(int));

    const int nb1 = (E + PE1 - 1) / PE1;

    hipMemsetAsync(cur1, 0, NSB_MAX * sizeof(int), stream);
    hipMemsetAsync(curF, 0, NSB_MAX * 8 * sizeof(int), stream);
    kPart1 <<<nb1, TPB, 0, stream>>>(src, dst, cur1, part1, E);
    kPart2 <<<2 * NSB, TPB, 0, stream>>>(cur1, part1, curF, partF);
    kConv1 <<<NFB, TPB, 0, stream>>>(x, partF, curF, W1, b1, h1p, deg, N);
    kConv2 <<<NFB, TPB, 0, stream>>>(h1p, partF, curF, deg, W2, b2, h2, N);
    kPoolMLP<<<G, TPB, 0, stream>>>(h2, batch, Wf1, bf1, Wf2, bf2, out, N);
}

// Round 7
// 417.756 us; speedup vs baseline: 1.1640x; 1.1640x over previous
//
#include <hip/hip_runtime.h>

// GNN_MLP R7: conv2 gathers 16B node_info (a0,a1,degf) from an 8MB array
// (L3-resident, ~50% L2) and recomputes h1 rows on the fly — the 32MB h1
// array (whose random 64B gathers cost E*64B=160MB of HBM in R3/R5, or 885MB
// thrashed in R6) is never materialized.
// Algebra: conv = segsum((h@W+b)[src],dst) = segsum(h[src])@W + indeg*b;
// h1 row is a rank-1-ish function of (aggx, deg) -> gather 3 scalars, not 16.

#define TPB 256
#define SBK_BITS 11           // super-bucket = 2048 nodes
#define NSB_MAX 256
#define CAP1 11264            // edges per super-bucket (mean ~10240, +10 sigma)
#define PE1 8192              // edges per pass-1 block
#define BKT_BITS 8
#define BKT 256               // nodes per fine bucket
#define CAPF 1536             // edges per fine bucket (mean 1280, +7 sigma)
#define ASTRIDE 17            // conv2 LDS acc node-row stride (bank-spread)

__device__ __forceinline__ float reluf(float v) { return v > 0.f ? v : 0.f; }

// pass 1: partition edges into 2048-node super-buckets, word = src<<11 | dst&2047
__global__ void kPart1(const int* __restrict__ src, const int* __restrict__ dst,
                       int* __restrict__ cur1, int* __restrict__ part1, int E) {
    __shared__ int h[NSB_MAX];
    h[threadIdx.x] = 0;
    __syncthreads();
    int base = blockIdx.x * PE1;
    int end = base + PE1 < E ? base + PE1 : E;
    for (int e = base + threadIdx.x; e < end; e += TPB)
        atomicAdd(&h[dst[e] >> SBK_BITS], 1);
    __syncthreads();
    {
        int c = h[threadIdx.x];
        if (c) h[threadIdx.x] = threadIdx.x * CAP1 + atomicAdd(&cur1[threadIdx.x], c);
    }
    __syncthreads();
    for (int e = base + threadIdx.x; e < end; e += TPB) {
        int d = dst[e];
        int sb = d >> SBK_BITS;
        int pos = atomicAdd(&h[sb], 1);
        if (pos < (sb + 1) * CAP1)
            part1[pos] = (src[e] << SBK_BITS) | (d & 2047);
    }
}

// pass 2: split each super-bucket into 8 fine buckets; 2 blocks per super.
// out word = src<<8 | dst&255.
__global__ void kPart2(const int* __restrict__ cur1, const int* __restrict__ part1,
                       int* __restrict__ curF, int* __restrict__ partF) {
    int sb = blockIdx.x >> 1, half = blockIdx.x & 1;
    int cnt = cur1[sb]; if (cnt > CAP1) cnt = CAP1;
    int mid = (cnt + 1) >> 1;
    int rs = sb * CAP1 + (half ? mid : 0);
    int re = sb * CAP1 + (half ? cnt : mid);
    __shared__ int hw[4][8];
    __shared__ int cbase[8];
    if (threadIdx.x < 32) hw[threadIdx.x >> 3][threadIdx.x & 7] = 0;
    __syncthreads();
    int wv = threadIdx.x >> 6;
    for (int i = rs + threadIdx.x; i < re; i += TPB)
        atomicAdd(&hw[wv][(part1[i] >> 8) & 7], 1);
    __syncthreads();
    if (threadIdx.x < 8) {
        int c = hw[0][threadIdx.x] + hw[1][threadIdx.x] + hw[2][threadIdx.x] + hw[3][threadIdx.x];
        int fb = sb * 8 + threadIdx.x;
        cbase[threadIdx.x] = fb * CAPF + (c ? atomicAdd(&curF[fb], c) : 0);
    }
    __syncthreads();
    for (int i = rs + threadIdx.x; i < re; i += TPB) {
        int w = part1[i];
        int f = (w >> 8) & 7;
        int pos = atomicAdd(&cbase[f], 1);
        if (pos < (sb * 8 + f + 1) * CAPF)
            partF[pos] = ((w >> 11) << 8) | (w & 255);
    }
}

// conv1: one block per fine bucket; LDS-accumulate raw x + degree;
// emit node_info[i] = (a0, a1, degf, 0). No h1 materialization.
__global__ void __launch_bounds__(TPB, 8)
kConv1(const float* __restrict__ x, const int* __restrict__ partF,
       const int* __restrict__ curF, float4* __restrict__ node_info, int N) {
    __shared__ float ax[BKT * 3];
    __shared__ int cnt[BKT];
    int b = blockIdx.x, node0 = b << BKT_BITS;
    ax[3 * threadIdx.x] = 0.f; ax[3 * threadIdx.x + 1] = 0.f;
    ax[BKT * 2 + threadIdx.x] = 0.f;
    cnt[threadIdx.x] = 0;
    __syncthreads();
    int rs = b * CAPF;
    int ec = curF[b]; if (ec > CAPF) ec = CAPF;
    int re = rs + ec;
    for (int e = rs + threadIdx.x; e < re; e += TPB) {
        int w = partF[e];
        int s = w >> BKT_BITS, l = w & (BKT - 1);
        float2 xv = ((const float2*)x)[s];
        atomicAdd(&ax[3 * l], xv.x);
        atomicAdd(&ax[3 * l + 1], xv.y);
        atomicAdd(&cnt[l], 1);
    }
    __syncthreads();
    int l = threadIdx.x;
    int i = node0 + l;
    if (i < N) {
        float2 s2 = ((const float2*)x)[i];
        node_info[i] = make_float4(ax[3 * l] + s2.x, ax[3 * l + 1] + s2.y,
                                   (float)(cnt[l] + 1), 0.f);
    }
}

// conv2: per edge gather 16B node_info[src] (8MB array -> L2/L3), recompute
// h1 row on the fly (32 fma + 16 relu), LDS-accumulate; epilogue W2+relu -> h2.
__global__ void __launch_bounds__(TPB, 8)
kConv2(const float4* __restrict__ node_info, const int* __restrict__ partF,
       const int* __restrict__ curF,
       const float* __restrict__ W1, const float* __restrict__ b1,
       const float* __restrict__ W2, const float* __restrict__ b2,
       float* __restrict__ h2, int N) {
    __shared__ float acc[BKT * ASTRIDE];   // 17.4 KB
    int b = blockIdx.x, node0 = b << BKT_BITS;
    for (int i = threadIdx.x; i < BKT * ASTRIDE; i += TPB) acc[i] = 0.f;
    __syncthreads();
    int rs = b * CAPF;
    int ec = curF[b]; if (ec > CAPF) ec = CAPF;
    int re = rs + ec;
    for (int e = rs + threadIdx.x; e < re; e += TPB) {
        int w = partF[e];
        int s = w >> BKT_BITS, l = w & (BKT - 1);
        float4 ni = node_info[s];
        float* a = &acc[l * ASTRIDE];
#pragma unroll
        for (int j = 0; j < 16; j++) {
            float hj = reluf(fmaf(ni.x, W1[j], fmaf(ni.y, W1[16 + j], ni.z * b1[j])));
            atomicAdd(a + j, hj);
        }
    }
    __syncthreads();
    int l = threadIdx.x;
    int i = node0 + l;
    if (i < N) {
        float4 ni = node_info[i];
        float a[16];
        const float* al = &acc[l * ASTRIDE];
#pragma unroll
        for (int j = 0; j < 16; j++) {
            float hj = reluf(fmaf(ni.x, W1[j], fmaf(ni.y, W1[16 + j], ni.z * b1[j])));
            a[j] = al[j] + hj;                    // + self-loop message
        }
        float degf = ni.z;
        float4* ov = (float4*)(h2 + 32 * (size_t)i);
#pragma unroll
        for (int q = 0; q < 8; q++) {
            float4 r;
            float* rp = &r.x;
#pragma unroll
            for (int jj = 0; jj < 4; jj++) {
                int j = 4 * q + jj;
                float vv = degf * b2[j];
#pragma unroll
                for (int k = 0; k < 16; k++) vv = fmaf(a[k], W2[k * 32 + j], vv);
                rp[jj] = reluf(vv);
            }
            ov[q] = r;
        }
    }
}

__device__ __forceinline__ int lower_bound(const int* __restrict__ a, int n, int v) {
    int lo = 0, hi = n;
    while (lo < hi) {
        int m = (lo + hi) >> 1;
        if (a[m] < v) lo = m + 1; else hi = m;
    }
    return lo;
}

// mean pool per graph (batch sorted -> binary search range) + fused MLP head
__global__ void kPoolMLP(const float* __restrict__ h2, const int* __restrict__ batch,
                         const float* __restrict__ Wf1, const float* __restrict__ bf1,
                         const float* __restrict__ Wf2, const float* __restrict__ bf2,
                         float* __restrict__ out, int N) {
    int g = blockIdx.x;
    int lo = lower_bound(batch, N, g);
    int hi = lower_bound(batch, N, g + 1);
    int cnt = hi - lo;
    int f = threadIdx.x & 31;
    int r = threadIdx.x >> 5;
    float acc = 0.f;
    for (int n = lo + r; n < hi; n += 8)
        acc += h2[32 * (size_t)n + f];
    __shared__ float s[8][33];
    __shared__ float p[32];
    __shared__ float v16[16];
    s[r][f] = acc;
    __syncthreads();
    if (r == 0) {
        float t = 0.f;
#pragma unroll
        for (int q = 0; q < 8; q++) t += s[q][f];
        p[f] = t / (float)(cnt > 1 ? cnt : 1);
    }
    __syncthreads();
    if (threadIdx.x < 16) {
        int j = threadIdx.x;
        float v = bf1[j];
#pragma unroll
        for (int i = 0; i < 32; i++) v = fmaf(p[i], Wf1[i * 16 + j], v);
        v16[j] = reluf(v);
    }
    __syncthreads();
    if (threadIdx.x == 0) {
        float a = bf2[0];
#pragma unroll
        for (int j = 0; j < 16; j++) a = fmaf(v16[j], Wf2[j], a);
        out[g] = a;
    }
}

static inline size_t align256(size_t v) { return (v + 255) & ~(size_t)255; }

extern "C" void kernel_launch(void* const* d_in, const int* in_sizes, int n_in,
                              void* d_out, int out_size, void* d_ws, size_t ws_size,
                              hipStream_t stream) {
    const float* x    = (const float*)d_in[0];
    const int*   ei   = (const int*)d_in[1];
    const int*   batch= (const int*)d_in[2];
    const float* W1   = (const float*)d_in[3];
    const float* b1   = (const float*)d_in[4];
    const float* W2   = (const float*)d_in[5];
    const float* b2   = (const float*)d_in[6];
    const float* Wf1  = (const float*)d_in[7];
    const float* bf1  = (const float*)d_in[8];
    const float* Wf2  = (const float*)d_in[9];
    const float* bf2  = (const float*)d_in[10];
    float* out = (float*)d_out;

    const int N = in_sizes[0] / 2;
    const int E = in_sizes[1] / 2;
    const int G = out_size;
    const int* src = ei;        // edge_index[0]
    const int* dst = ei + E;    // edge_index[1]

    const int NSB = (N + 2047) >> SBK_BITS;          // super-buckets (<=256)
    const int NFB = (N + BKT - 1) >> BKT_BITS;       // fine buckets

    // workspace layout; part1 overlays h2 (disjoint lifetimes)
    char* w = (char*)d_ws;
    int*    cur1 = (int*)w;      w += align256((size_t)NSB_MAX * sizeof(int));
    int*    curF = (int*)w;      w += align256((size_t)NSB_MAX * 8 * sizeof(int));
    float4* ninfo = (float4*)w;  w += align256((size_t)N * sizeof(float4));
    float*  h2   = (float*)w;    w += align256((size_t)N * 32 * sizeof(float));
    int*    part1 = (int*)h2;    // overlay: dead before kConv2 writes h2
    int*    partF = (int*)w;     w += align256((size_t)NSB_MAX * 8 * CAPF * sizeof(int));

    const int nb1 = (E + PE1 - 1) / PE1;

    hipMemsetAsync(cur1, 0, NSB_MAX * sizeof(int), stream);
    hipMemsetAsync(curF, 0, NSB_MAX * 8 * sizeof(int), stream);
    kPart1 <<<nb1, TPB, 0, stream>>>(src, dst, cur1, part1, E);
    kPart2 <<<2 * NSB, TPB, 0, stream>>>(cur1, part1, curF, partF);
    kConv1 <<<NFB, TPB, 0, stream>>>(x, partF, curF, ninfo, N);
    kConv2 <<<NFB, TPB, 0, stream>>>(ninfo, partF, curF, W1, b1, W2, b2, h2, N);
    kPoolMLP<<<G, TPB, 0, stream>>>(h2, batch, Wf1, bf1, Wf2, bf2, out, N);
}